// Round 16
// baseline (536.157 us; speedup 1.0000x reference)
//
#include <hip/hip_runtime.h>
#include <hip/hip_bf16.h>
#include <cstddef>

// Problem constants
#define BB 256
#define XX 512
#define HH 1024
#define RR 512
#define MM 512
// derived
#define KCAT 2048          // X + H + R
#define KXC 1536           // X + H
#define NFULL 4608         // R + 4H
#define NG 1536            // R + H

// d_out offsets (floats)
#define OFF_NH (BB*1536)                 // 393216
#define OFF_NC (OFF_NH + BB*HH)          // 655360
#define OFF_HM (OFF_NC + BB*HH)          // 917504

typedef __attribute__((ext_vector_type(8))) short bf16x8;
typedef __attribute__((ext_vector_type(4))) short s16x4;
typedef __attribute__((ext_vector_type(4))) float f32x4;

__device__ __forceinline__ float sigm(float x) { return 1.0f / (1.0f + expf(-x)); }

// fp32 -> bf16 bits, round-to-nearest-even (finite values)
__device__ __forceinline__ unsigned short f2bf(float f) {
    unsigned u = __float_as_uint(f);
    u = u + 0x7fffu + ((u >> 16) & 1u);
    return (unsigned short)(u >> 16);
}
__device__ __forceinline__ float bf2f(unsigned short h) {
    return __uint_as_float((unsigned)h << 16);
}

// ===========================================================================
// ===============            MAIN (pre-split) PATH            ===============
// ===========================================================================

// Straight convert: src [n] f32 -> hi/lo bf16 (same layout). 8 elems/thread.
__global__ __launch_bounds__(256) void convw_k(const float* __restrict__ src,
                                               short* __restrict__ hi,
                                               short* __restrict__ lo,
                                               int n8) {
    int i = blockIdx.x * 256 + threadIdx.x;
    if (i >= n8) return;
    size_t e0 = (size_t)i * 8;
    short hs[8], ls[8];
    #pragma unroll
    for (int q = 0; q < 2; ++q) {
        float4 v = reinterpret_cast<const float4*>(src + e0)[q];
        float f[4] = {v.x, v.y, v.z, v.w};
        #pragma unroll
        for (int e = 0; e < 4; ++e) {
            unsigned short hb = f2bf(f[e]);
            hs[q * 4 + e] = (short)hb;
            ls[q * 4 + e] = (short)f2bf(f[e] - bf2f(hb));
        }
    }
    *reinterpret_cast<bf16x8*>(hi + e0) = *reinterpret_cast<bf16x8*>(&hs[0]);
    *reinterpret_cast<bf16x8*>(lo + e0) = *reinterpret_cast<bf16x8*>(&ls[0]);
}

// Transpose-convert: W [Kdim][Ndim] f32 -> Thi/Tlo [Ndim][Kdim] bf16.
// 64x64 tiles; LDS staged.
__global__ __launch_bounds__(256) void convt_k(const float* __restrict__ W,
                                               int Kdim, int Ndim,
                                               short* __restrict__ Thi,
                                               short* __restrict__ Tlo) {
    __shared__ __align__(16) short lh[64][72];
    __shared__ __align__(16) short ll[64][72];
    const int tid = threadIdx.x;
    const int k0 = blockIdx.x * 64, n0 = blockIdx.y * 64;
    {
        int kr = (tid >> 4) * 4;          // 0..60
        int nc = (tid & 15) * 4;          // 0..60
        #pragma unroll
        for (int i = 0; i < 4; ++i) {
            float4 v = *reinterpret_cast<const float4*>(W + (size_t)(k0 + kr + i) * Ndim + n0 + nc);
            float f[4] = {v.x, v.y, v.z, v.w};
            #pragma unroll
            for (int e = 0; e < 4; ++e) {
                unsigned short hb = f2bf(f[e]);
                lh[nc + e][kr + i] = (short)hb;
                ll[nc + e][kr + i] = (short)f2bf(f[e] - bf2f(hb));
            }
        }
    }
    __syncthreads();
    {
        int nl = tid >> 2;                // 0..63
        int kq = (tid & 3) * 16;          // 0..48
        size_t base = (size_t)(n0 + nl) * Kdim + k0 + kq;
        *reinterpret_cast<bf16x8*>(Thi + base)     = *reinterpret_cast<const bf16x8*>(&lh[nl][kq]);
        *reinterpret_cast<bf16x8*>(Thi + base + 8) = *reinterpret_cast<const bf16x8*>(&lh[nl][kq + 8]);
        *reinterpret_cast<bf16x8*>(Tlo + base)     = *reinterpret_cast<const bf16x8*>(&ll[nl][kq]);
        *reinterpret_cast<bf16x8*>(Tlo + base + 8) = *reinterpret_cast<const bf16x8*>(&ll[nl][kq + 8]);
    }
}

// prep: cat[:,0:1536] = [x|c] (hi/lo); x also into gat[:,0:512], xnc[:,0:512]
__global__ __launch_bounds__(256) void prep_k(const float* __restrict__ x,
                                              const float* __restrict__ c,
                                              short* __restrict__ cat_hi, short* __restrict__ cat_lo,
                                              short* __restrict__ gat_hi, short* __restrict__ gat_lo,
                                              short* __restrict__ xnc_hi, short* __restrict__ xnc_lo) {
    int i = blockIdx.x * 256 + threadIdx.x;       // B*1536/4 threads
    int e0 = i * 4;
    int b = e0 / KXC, q = e0 - b * KXC;
    float4 v = (q < XX) ? *reinterpret_cast<const float4*>(x + (size_t)b * XX + q)
                        : *reinterpret_cast<const float4*>(c + (size_t)b * HH + (q - XX));
    float f[4] = {v.x, v.y, v.z, v.w};
    s16x4 hv, lv;
    #pragma unroll
    for (int e = 0; e < 4; ++e) {
        unsigned short hb = f2bf(f[e]);
        hv[e] = (short)hb;
        lv[e] = (short)f2bf(f[e] - bf2f(hb));
    }
    *reinterpret_cast<s16x4*>(cat_hi + (size_t)b * KCAT + q) = hv;
    *reinterpret_cast<s16x4*>(cat_lo + (size_t)b * KCAT + q) = lv;
    if (q < XX) {
        *reinterpret_cast<s16x4*>(gat_hi + (size_t)b * KCAT + q) = hv;
        *reinterpret_cast<s16x4*>(gat_lo + (size_t)b * KCAT + q) = lv;
        *reinterpret_cast<s16x4*>(xnc_hi + (size_t)b * KXC + q) = hv;
        *reinterpret_cast<s16x4*>(xnc_lo + (size_t)b * KXC + q) = lv;
    }
}

// MFMA GEMM on pre-split bf16 hi/lo operands.
// THE single change vs round-15 anchor: register double-buffering — next
// K-tile's global loads issued right after the barrier, so their ~200-500cy
// latency hides under the MFMA phase instead of being exposed at the top of
// the next iteration. +16 VGPRs, no occupancy step.
// EPI 0: C[row*ldc+col] = acc + bias[col]
// EPI 1: gate: e=cat[row][512+col]; gat[row][512+col] = split(e*sigm(acc+bias))
template<int EPI>
__global__ __launch_bounds__(256) void mgemm_ps(const short* __restrict__ Ahi,
                                                const short* __restrict__ Alo, int lda,
                                                const short* __restrict__ Bhi,
                                                const short* __restrict__ Blo,
                                                const float* __restrict__ bias,
                                                float* __restrict__ C, int ldc,
                                                const short* __restrict__ cat_hi,
                                                const short* __restrict__ cat_lo,
                                                short* __restrict__ gat_hi,
                                                short* __restrict__ gat_lo,
                                                int K) {
    __shared__ __align__(16) short Ah[64][72];
    __shared__ __align__(16) short Al[64][72];
    __shared__ __align__(16) short Bh[64][72];
    __shared__ __align__(16) short Bl[64][72];

    const int tid = threadIdx.x;
    const int row0 = blockIdx.y * 64, col0 = blockIdx.x * 64;
    const int lane = tid & 63, w = tid >> 6;
    const int rm = (w >> 1) * 32, cn = (w & 1) * 32;
    const int fr = lane & 15;
    const int kg = lane >> 4;

    const int ar = tid >> 2;              // 0..63
    const int akq = (tid & 3) * 16;       // 0..48

    f32x4 acc[2][2] = {};
    int4 pa[4], pb[4];                    // prefetch regs: [0,1]=hi, [2,3]=lo

    const short* aH = Ahi + (size_t)(row0 + ar) * lda + akq;
    const short* aL = Alo + (size_t)(row0 + ar) * lda + akq;
    const short* bH = Bhi + (size_t)(col0 + ar) * K + akq;
    const short* bL = Blo + (size_t)(col0 + ar) * K + akq;

    // prologue: load tile 0
    pa[0] = *reinterpret_cast<const int4*>(aH);
    pa[1] = *reinterpret_cast<const int4*>(aH + 8);
    pa[2] = *reinterpret_cast<const int4*>(aL);
    pa[3] = *reinterpret_cast<const int4*>(aL + 8);
    pb[0] = *reinterpret_cast<const int4*>(bH);
    pb[1] = *reinterpret_cast<const int4*>(bH + 8);
    pb[2] = *reinterpret_cast<const int4*>(bL);
    pb[3] = *reinterpret_cast<const int4*>(bL + 8);

    for (int k0 = 0; k0 < K; k0 += 64) {
        // write staged regs to LDS
        *reinterpret_cast<int4*>(&Ah[ar][akq])     = pa[0];
        *reinterpret_cast<int4*>(&Ah[ar][akq + 8]) = pa[1];
        *reinterpret_cast<int4*>(&Al[ar][akq])     = pa[2];
        *reinterpret_cast<int4*>(&Al[ar][akq + 8]) = pa[3];
        *reinterpret_cast<int4*>(&Bh[ar][akq])     = pb[0];
        *reinterpret_cast<int4*>(&Bh[ar][akq + 8]) = pb[1];
        *reinterpret_cast<int4*>(&Bl[ar][akq])     = pb[2];
        *reinterpret_cast<int4*>(&Bl[ar][akq + 8]) = pb[3];
        __syncthreads();
        // issue next tile's loads (latency hidden under MFMA phase)
        if (k0 + 64 < K) {
            int kc = k0 + 64;
            pa[0] = *reinterpret_cast<const int4*>(aH + kc);
            pa[1] = *reinterpret_cast<const int4*>(aH + kc + 8);
            pa[2] = *reinterpret_cast<const int4*>(aL + kc);
            pa[3] = *reinterpret_cast<const int4*>(aL + kc + 8);
            pb[0] = *reinterpret_cast<const int4*>(bH + kc);
            pb[1] = *reinterpret_cast<const int4*>(bH + kc + 8);
            pb[2] = *reinterpret_cast<const int4*>(bL + kc);
            pb[3] = *reinterpret_cast<const int4*>(bL + kc + 8);
        }
        // MFMA phase
        #pragma unroll
        for (int ks = 0; ks < 64; ks += 32) {
            bf16x8 ah[2], al[2], bh[2], bl[2];
            #pragma unroll
            for (int mf = 0; mf < 2; ++mf) {
                ah[mf] = *reinterpret_cast<const bf16x8*>(&Ah[rm + mf * 16 + fr][ks + kg * 8]);
                al[mf] = *reinterpret_cast<const bf16x8*>(&Al[rm + mf * 16 + fr][ks + kg * 8]);
            }
            #pragma unroll
            for (int nf = 0; nf < 2; ++nf) {
                bh[nf] = *reinterpret_cast<const bf16x8*>(&Bh[cn + nf * 16 + fr][ks + kg * 8]);
                bl[nf] = *reinterpret_cast<const bf16x8*>(&Bl[cn + nf * 16 + fr][ks + kg * 8]);
            }
            #pragma unroll
            for (int mf = 0; mf < 2; ++mf)
                #pragma unroll
                for (int nf = 0; nf < 2; ++nf) {
                    acc[mf][nf] = __builtin_amdgcn_mfma_f32_16x16x32_bf16(ah[mf], bh[nf], acc[mf][nf], 0, 0, 0);
                    acc[mf][nf] = __builtin_amdgcn_mfma_f32_16x16x32_bf16(ah[mf], bl[nf], acc[mf][nf], 0, 0, 0);
                    acc[mf][nf] = __builtin_amdgcn_mfma_f32_16x16x32_bf16(al[mf], bh[nf], acc[mf][nf], 0, 0, 0);
                }
        }
        __syncthreads();
    }

    #pragma unroll
    for (int mf = 0; mf < 2; ++mf)
        #pragma unroll
        for (int nf = 0; nf < 2; ++nf)
            #pragma unroll
            for (int i = 0; i < 4; ++i) {
                int row = row0 + rm + mf * 16 + kg * 4 + i;
                int col = col0 + cn + nf * 16 + fr;
                float v = acc[mf][nf][i] + bias[col];
                if (EPI == 0) {
                    C[(size_t)row * ldc + col] = v;
                } else {
                    size_t base = (size_t)row * KCAT + XX + col;
                    float e = bf2f((unsigned short)cat_hi[base]) + bf2f((unsigned short)cat_lo[base]);
                    float gv = e * sigm(v);
                    unsigned short hb = f2bf(gv);
                    gat_hi[base] = (short)hb;
                    gat_lo[base] = (short)f2bf(gv - bf2f(hb));
                }
            }
}

// fused softmax + h_entry: block b, 512 threads.
__global__ __launch_bounds__(512) void smhe_k(const float* __restrict__ rh,
                                              const float* __restrict__ hmem,
                                              float* __restrict__ hidx,
                                              short* __restrict__ cat_hi,
                                              short* __restrict__ cat_lo) {
    __shared__ float red[8];
    __shared__ float red2[8];
    __shared__ float wiL[MM];
    int b = blockIdx.x, t = threadIdx.x;
    float v = rh[(size_t)b * MM + t];
    float m = v;
    #pragma unroll
    for (int off = 1; off < 64; off <<= 1) m = fmaxf(m, __shfl_xor(m, off));
    int wid = t >> 6, lane = t & 63;
    if (lane == 0) red[wid] = m;
    __syncthreads();
    float mm = red[0];
    #pragma unroll
    for (int i = 1; i < 8; ++i) mm = fmaxf(mm, red[i]);
    float e = expf(v - mm);
    float s = e;
    #pragma unroll
    for (int off = 1; off < 64; off <<= 1) s += __shfl_xor(s, off);
    if (lane == 0) red2[wid] = s;
    __syncthreads();
    float tot = red2[0];
    #pragma unroll
    for (int i = 1; i < 8; ++i) tot += red2[i];
    float wi = e / tot;
    hidx[(size_t)b * MM + t] = wi;
    wiL[t] = wi;
    __syncthreads();
    // h_entry[b][t] = sum_m wi[m] * hmem[b][m][t]
    const float* hm = hmem + (size_t)b * MM * RR + t;
    float acc = 0.f;
    #pragma unroll 8
    for (int m2 = 0; m2 < MM; ++m2) acc += wiL[m2] * hm[(size_t)m2 * RR];
    size_t base = (size_t)b * KCAT + KXC + t;
    unsigned short hb = f2bf(acc);
    cat_hi[base] = (short)hb;
    cat_lo[base] = (short)f2bf(acc - bf2f(hb));
}

// LSTM elementwise; writes new_r/new_h/new_c and xnc[:,512:1536] = split(new_c)
__global__ __launch_bounds__(256) void lstm_k(const float* __restrict__ pre,
                                              const float* __restrict__ c,
                                              const short* __restrict__ cat_hi,
                                              const short* __restrict__ cat_lo,
                                              float* __restrict__ out,
                                              short* __restrict__ xnc_hi,
                                              short* __restrict__ xnc_lo) {
    int idx = blockIdx.x * 256 + threadIdx.x;   // B*1536
    int b = idx / 1536, q = idx - b * 1536;
    const float* p = pre + (size_t)b * NFULL;
    if (q < HH) {
        float iv = p[q], jv = p[HH + q], fv = p[2 * HH + q], ov = p[3 * HH + q];
        float cc = c[(size_t)b * HH + q];
        float nc = tanhf(cc * sigm(fv + 1.0f) + sigm(iv) * tanhf(jv));
        float nh = nc * sigm(ov);
        out[(size_t)b * 1536 + q] = nh;
        out[OFF_NH + (size_t)b * HH + q] = nh;
        out[OFF_NC + (size_t)b * HH + q] = nc;
        unsigned short hb = f2bf(nc);
        xnc_hi[(size_t)b * KXC + XX + q] = (short)hb;
        xnc_lo[(size_t)b * KXC + XX + q] = (short)f2bf(nc - bf2f(hb));
    } else {
        int r = q - HH;
        float om = p[4 * HH + r];
        size_t base = (size_t)b * KCAT + KXC + r;
        float he = bf2f((unsigned short)cat_hi[base]) + bf2f((unsigned short)cat_lo[base]);
        out[(size_t)b * 1536 + HH + r] = he * sigm(om);
    }
}

// new_hmem = w_val[:,None,:]*w_idx[:,:,None] + hmem*(1-w_idx)
// (grid-stride form: lockstep dense streaming — measured optimal)
__global__ __launch_bounds__(256) void hmemupd_k(const float* __restrict__ hmem,
                                                 const float* __restrict__ wval,
                                                 const float* __restrict__ widx,
                                                 float* __restrict__ outhm) {
    size_t n4 = (size_t)BB * MM * RR / 4;
    size_t stride = (size_t)gridDim.x * blockDim.x;
    for (size_t i = (size_t)blockIdx.x * blockDim.x + threadIdx.x; i < n4; i += stride) {
        size_t e = i * 4;
        int r = (int)(e & (RR - 1));
        int m = (int)((e >> 9) & (MM - 1));
        int b = (int)(e >> 18);
        float wi = widx[(size_t)b * MM + m];
        float om = 1.0f - wi;
        float4 hv = *reinterpret_cast<const float4*>(hmem + e);
        float4 wv = *reinterpret_cast<const float4*>(wval + (size_t)b * RR + r);
        float4 o;
        o.x = wv.x * wi + hv.x * om;
        o.y = wv.y * wi + hv.y * om;
        o.z = wv.z * wi + hv.z * om;
        o.w = wv.w * wi + hv.w * om;
        *reinterpret_cast<float4*>(outhm + e) = o;
    }
}

// ===========================================================================
// ===============     FALLBACK (round-3, split-in-loop)       ===============
// ===========================================================================

__global__ __launch_bounds__(256) void prep3_k(const float* __restrict__ x,
                                               const float* __restrict__ c,
                                               float* __restrict__ concatb,
                                               float* __restrict__ gated) {
    int idx = blockIdx.x * 256 + threadIdx.x;
    int b = idx / KXC, q = idx - b * KXC;
    float v;
    if (q < XX) { v = x[b * XX + q]; gated[(size_t)b * KCAT + q] = v; }
    else v = c[b * HH + (q - XX)];
    concatb[(size_t)b * KCAT + q] = v;
}

template<int AMODE, int BLAYOUT, int EPI>
__global__ __launch_bounds__(256) void mgemm3_k(const float* __restrict__ A0,
                                                const float* __restrict__ A1,
                                                const float* __restrict__ W,
                                                const float* __restrict__ bias,
                                                float* __restrict__ C,
                                                const float* __restrict__ E,
                                                int N, int K) {
    __shared__ __align__(16) short Ah[64][72];
    __shared__ __align__(16) short Al[64][72];
    __shared__ __align__(16) short Bh[64][72];
    __shared__ __align__(16) short Bl[64][72];
    const int tid = threadIdx.x;
    const int row0 = blockIdx.y * 64, col0 = blockIdx.x * 64;
    const int lane = tid & 63, w = tid >> 6;
    const int rm = (w >> 1) * 32, cn = (w & 1) * 32;
    const int fr = lane & 15, kg = lane >> 4;
    const int ar = tid >> 2, akq = (tid & 3) * 16;
    const int bkk = (tid >> 4) * 4, bnn = (tid & 15) * 4;
    f32x4 acc[2][2] = {};
    for (int k0 = 0; k0 < K; k0 += 64) {
        {
            const float* src;
            if (AMODE == 0) src = A0 + (size_t)(row0 + ar) * K + k0 + akq;
            else {
                int gk = k0 + akq;
                src = (gk < XX) ? (A0 + (size_t)(row0 + ar) * XX + gk)
                                : (A1 + (size_t)(row0 + ar) * HH + (gk - XX));
            }
            short hs[16], ls[16];
            #pragma unroll
            for (int q = 0; q < 4; ++q) {
                float4 v = reinterpret_cast<const float4*>(src)[q];
                float f[4] = {v.x, v.y, v.z, v.w};
                #pragma unroll
                for (int e = 0; e < 4; ++e) {
                    unsigned short hb = f2bf(f[e]);
                    hs[q * 4 + e] = (short)hb;
                    ls[q * 4 + e] = (short)f2bf(f[e] - bf2f(hb));
                }
            }
            *reinterpret_cast<bf16x8*>(&Ah[ar][akq])     = *reinterpret_cast<bf16x8*>(&hs[0]);
            *reinterpret_cast<bf16x8*>(&Ah[ar][akq + 8]) = *reinterpret_cast<bf16x8*>(&hs[8]);
            *reinterpret_cast<bf16x8*>(&Al[ar][akq])     = *reinterpret_cast<bf16x8*>(&ls[0]);
            *reinterpret_cast<bf16x8*>(&Al[ar][akq + 8]) = *reinterpret_cast<bf16x8*>(&ls[8]);
        }
        if (BLAYOUT == 1) {
            const float* src = W + (size_t)(col0 + ar) * K + k0 + akq;
            short hs[16], ls[16];
            #pragma unroll
            for (int q = 0; q < 4; ++q) {
                float4 v = reinterpret_cast<const float4*>(src)[q];
                float f[4] = {v.x, v.y, v.z, v.w};
                #pragma unroll
                for (int e = 0; e < 4; ++e) {
                    unsigned short hb = f2bf(f[e]);
                    hs[q * 4 + e] = (short)hb;
                    ls[q * 4 + e] = (short)f2bf(f[e] - bf2f(hb));
                }
            }
            *reinterpret_cast<bf16x8*>(&Bh[ar][akq])     = *reinterpret_cast<bf16x8*>(&hs[0]);
            *reinterpret_cast<bf16x8*>(&Bh[ar][akq + 8]) = *reinterpret_cast<bf16x8*>(&hs[8]);
            *reinterpret_cast<bf16x8*>(&Bl[ar][akq])     = *reinterpret_cast<bf16x8*>(&ls[0]);
            *reinterpret_cast<bf16x8*>(&Bl[ar][akq + 8]) = *reinterpret_cast<bf16x8*>(&ls[8]);
        } else {
            float4 r0 = *reinterpret_cast<const float4*>(W + (size_t)(k0 + bkk + 0) * N + col0 + bnn);
            float4 r1 = *reinterpret_cast<const float4*>(W + (size_t)(k0 + bkk + 1) * N + col0 + bnn);
            float4 r2 = *reinterpret_cast<const float4*>(W + (size_t)(k0 + bkk + 2) * N + col0 + bnn);
            float4 r3 = *reinterpret_cast<const float4*>(W + (size_t)(k0 + bkk + 3) * N + col0 + bnn);
            float col[4][4] = {{r0.x, r1.x, r2.x, r3.x}, {r0.y, r1.y, r2.y, r3.y},
                               {r0.z, r1.z, r2.z, r3.z}, {r0.w, r1.w, r2.w, r3.w}};
            #pragma unroll
            for (int j = 0; j < 4; ++j) {
                s16x4 hv, lv;
                #pragma unroll
                for (int e = 0; e < 4; ++e) {
                    unsigned short hb = f2bf(col[j][e]);
                    hv[e] = (short)hb;
                    lv[e] = (short)f2bf(col[j][e] - bf2f(hb));
                }
                *reinterpret_cast<s16x4*>(&Bh[bnn + j][bkk]) = hv;
                *reinterpret_cast<s16x4*>(&Bl[bnn + j][bkk]) = lv;
            }
        }
        __syncthreads();
        #pragma unroll
        for (int ks = 0; ks < 64; ks += 32) {
            bf16x8 ah[2], al[2], bh[2], bl[2];
            #pragma unroll
            for (int mf = 0; mf < 2; ++mf) {
                ah[mf] = *reinterpret_cast<const bf16x8*>(&Ah[rm + mf * 16 + fr][ks + kg * 8]);
                al[mf] = *reinterpret_cast<const bf16x8*>(&Al[rm + mf * 16 + fr][ks + kg * 8]);
            }
            #pragma unroll
            for (int nf = 0; nf < 2; ++nf) {
                bh[nf] = *reinterpret_cast<const bf16x8*>(&Bh[cn + nf * 16 + fr][ks + kg * 8]);
                bl[nf] = *reinterpret_cast<const bf16x8*>(&Bl[cn + nf * 16 + fr][ks + kg * 8]);
            }
            #pragma unroll
            for (int mf = 0; mf < 2; ++mf)
                #pragma unroll
                for (int nf = 0; nf < 2; ++nf) {
                    acc[mf][nf] = __builtin_amdgcn_mfma_f32_16x16x32_bf16(ah[mf], bh[nf], acc[mf][nf], 0, 0, 0);
                    acc[mf][nf] = __builtin_amdgcn_mfma_f32_16x16x32_bf16(ah[mf], bl[nf], acc[mf][nf], 0, 0, 0);
                    acc[mf][nf] = __builtin_amdgcn_mfma_f32_16x16x32_bf16(al[mf], bh[nf], acc[mf][nf], 0, 0, 0);
                }
        }
        __syncthreads();
    }
    #pragma unroll
    for (int mf = 0; mf < 2; ++mf)
        #pragma unroll
        for (int nf = 0; nf < 2; ++nf)
            #pragma unroll
            for (int i = 0; i < 4; ++i) {
                int row = row0 + rm + mf * 16 + kg * 4 + i;
                int col = col0 + cn + nf * 16 + fr;
                float v = acc[mf][nf][i] + bias[col];
                if (EPI == 0) C[(size_t)row * N + col] = v;
                else {
                    size_t base = (size_t)row * KCAT + XX + col;
                    C[base] = E[base] * sigm(v);
                }
            }
}

__global__ __launch_bounds__(256) void softmax3_k(float* __restrict__ rh) {
    int b = blockIdx.x;
    float* row = rh + (size_t)b * MM;
    int t = threadIdx.x;
    float v0 = row[t], v1 = row[t + 256];
    float m = fmaxf(v0, v1);
    #pragma unroll
    for (int off = 1; off < 64; off <<= 1) m = fmaxf(m, __shfl_xor(m, off));
    __shared__ float red[8];
    int wid = t >> 6, lane = t & 63;
    if (lane == 0) red[wid] = m;
    __syncthreads();
    float mm = fmaxf(fmaxf(red[0], red[1]), fmaxf(red[2], red[3]));
    float e0 = expf(v0 - mm), e1 = expf(v1 - mm);
    float s = e0 + e1;
    #pragma unroll
    for (int off = 1; off < 64; off <<= 1) s += __shfl_xor(s, off);
    if (lane == 0) red[4 + wid] = s;
    __syncthreads();
    float inv = 1.0f / (red[4] + red[5] + red[6] + red[7]);
    row[t] = e0 * inv;
    row[t + 256] = e1 * inv;
}

__global__ __launch_bounds__(512) void hentry3_k(const float* __restrict__ hidx,
                                                 const float* __restrict__ hmem,
                                                 float* __restrict__ concatb) {
    int b = blockIdx.x;
    int r = threadIdx.x;
    __shared__ float wi[MM];
    wi[r] = hidx[(size_t)b * MM + r];
    __syncthreads();
    const float* hm = hmem + (size_t)b * MM * RR + r;
    float acc = 0.f;
    #pragma unroll 8
    for (int m = 0; m < MM; ++m) acc += wi[m] * hm[(size_t)m * RR];
    concatb[(size_t)b * KCAT + KXC + r] = acc;
}

__global__ __launch_bounds__(256) void lstm3_k(const float* __restrict__ pre,
                                               const float* __restrict__ c,
                                               const float* __restrict__ concatb,
                                               float* __restrict__ out) {
    int idx = blockIdx.x * 256 + threadIdx.x;
    int b = idx / 1536, q = idx - b * 1536;
    const float* p = pre + (size_t)b * NFULL;
    if (q < HH) {
        float iv = p[q], jv = p[HH + q], fv = p[2 * HH + q], ov = p[3 * HH + q];
        float cc = c[(size_t)b * HH + q];
        float nc = tanhf(cc * sigm(fv + 1.0f) + sigm(iv) * tanhf(jv));
        float nh = nc * sigm(ov);
        out[(size_t)b * 1536 + q] = nh;
        out[OFF_NH + (size_t)b * HH + q] = nh;
        out[OFF_NC + (size_t)b * HH + q] = nc;
    } else {
        int r = q - HH;
        float om = p[4 * HH + r];
        float he = concatb[(size_t)b * KCAT + KXC + r];
        out[(size_t)b * 1536 + HH + r] = he * sigm(om);
    }
}

// ===========================================================================
extern "C" void kernel_launch(void* const* d_in, const int* in_sizes, int n_in,
                              void* d_out, int out_size, void* d_ws, size_t ws_size,
                              hipStream_t stream) {
    const float* x      = (const float*)d_in[0];
    const float* c      = (const float*)d_in[2];
    const float* hmem   = (const float*)d_in[3];
    const float* W_full = (const float*)d_in[4];
    const float* bias   = (const float*)d_in[5];
    const float* W_full1= (const float*)d_in[6];
    const float* bias1  = (const float*)d_in[7];
    const float* trans_w= (const float*)d_in[8];
    const float* trans_b= (const float*)d_in[9];
    const float* fc_w   = (const float*)d_in[10];
    const float* fc_b   = (const float*)d_in[11];

    float* out = (float*)d_out;

    // ---- new-path workspace layout (bytes)
    constexpr size_t SZ_WT  = (size_t)NFULL * KCAT * 2;
    constexpr size_t SZ_WT1 = (size_t)NG * KCAT * 2;
    constexpr size_t SZ_FCW = (size_t)MM * KXC * 2;
    constexpr size_t SZ_TRW = (size_t)RR * KXC * 2;
    constexpr size_t SZ_CAT = (size_t)BB * KCAT * 2;
    constexpr size_t SZ_XNC = (size_t)BB * KXC * 2;
    constexpr size_t SZ_RH  = (size_t)BB * MM * 4;
    constexpr size_t SZ_PRE = (size_t)BB * NFULL * 4;
    constexpr size_t NEED = 2*SZ_WT + 2*SZ_WT1 + 2*SZ_FCW + 2*SZ_TRW
                          + 4*SZ_CAT + 2*SZ_XNC + 2*SZ_RH + SZ_PRE + SZ_RH;

    if (ws_size >= NEED) {
        char* p = (char*)d_ws;
        short* wt_hi  = (short*)p; p += SZ_WT;
        short* wt_lo  = (short*)p; p += SZ_WT;
        short* wt1_hi = (short*)p; p += SZ_WT1;
        short* wt1_lo = (short*)p; p += SZ_WT1;
        short* fcw_hi = (short*)p; p += SZ_FCW;
        short* fcw_lo = (short*)p; p += SZ_FCW;
        short* trw_hi = (short*)p; p += SZ_TRW;
        short* trw_lo = (short*)p; p += SZ_TRW;
        short* cat_hi = (short*)p; p += SZ_CAT;
        short* cat_lo = (short*)p; p += SZ_CAT;
        short* gat_hi = (short*)p; p += SZ_CAT;
        short* gat_lo = (short*)p; p += SZ_CAT;
        short* xnc_hi = (short*)p; p += SZ_XNC;
        short* xnc_lo = (short*)p; p += SZ_XNC;
        float* rh     = (float*)p; p += SZ_RH;
        float* hidx   = (float*)p; p += SZ_RH;
        float* pre    = (float*)p; p += SZ_PRE;
        float* wval   = (float*)p;

        // weight conversion (every call; deterministic)
        convt_k<<<dim3(KCAT / 64, NFULL / 64), 256, 0, stream>>>(W_full, KCAT, NFULL, wt_hi, wt_lo);
        convt_k<<<dim3(KCAT / 64, NG / 64), 256, 0, stream>>>(W_full1, KCAT, NG, wt1_hi, wt1_lo);
        convw_k<<<(MM * KXC / 8 + 255) / 256, 256, 0, stream>>>(fc_w, fcw_hi, fcw_lo, MM * KXC / 8);
        convw_k<<<(RR * KXC / 8 + 255) / 256, 256, 0, stream>>>(trans_w, trw_hi, trw_lo, RR * KXC / 8);

        prep_k<<<BB * KXC / 4 / 256, 256, 0, stream>>>(x, c, cat_hi, cat_lo, gat_hi, gat_lo, xnc_hi, xnc_lo);

        // read_head = [x|c] @ fc_w^T + fc_b
        mgemm_ps<0><<<dim3(MM / 64, BB / 64), 256, 0, stream>>>(
            cat_hi, cat_lo, KCAT, fcw_hi, fcw_lo, fc_b, rh, MM,
            nullptr, nullptr, nullptr, nullptr, KXC);

        smhe_k<<<BB, 512, 0, stream>>>(rh, hmem, hidx, cat_hi, cat_lo);

        // gate GEMM with split-epilogue into gat
        mgemm_ps<1><<<dim3(NG / 64, BB / 64), 256, 0, stream>>>(
            cat_hi, cat_lo, KCAT, wt1_hi, wt1_lo, bias1, nullptr, 0,
            cat_hi, cat_lo, gat_hi, gat_lo, KCAT);

        // pre = gated @ W_full + bias
        mgemm_ps<0><<<dim3(NFULL / 64, BB / 64), 256, 0, stream>>>(
            gat_hi, gat_lo, KCAT, wt_hi, wt_lo, bias, pre, NFULL,
            nullptr, nullptr, nullptr, nullptr, KCAT);

        lstm_k<<<BB * 1536 / 256, 256, 0, stream>>>(pre, c, cat_hi, cat_lo, out, xnc_hi, xnc_lo);

        // w_val = [x|new_c] @ trans_w^T + trans_b
        mgemm_ps<0><<<dim3(RR / 64, BB / 64), 256, 0, stream>>>(
            xnc_hi, xnc_lo, KXC, trw_hi, trw_lo, trans_b, wval, RR,
            nullptr, nullptr, nullptr, nullptr, KXC);

        // hmem blend
        hmemupd_k<<<4096, 256, 0, stream>>>(hmem, wval, hidx, out + OFF_HM);
    } else {
        // -------- fallback: round-3 path (~10 MB ws) --------
        float* ws   = (float*)d_ws;
        float* hidx    = ws;
        float* concatb = hidx + BB * MM;
        float* gated   = concatb + BB * KCAT;
        float* pre     = gated + BB * KCAT;
        float* wval    = pre + BB * NFULL;
        float* new_c   = out + OFF_NC;

        prep3_k<<<BB * KXC / 256, 256, 0, stream>>>(x, c, concatb, gated);
        mgemm3_k<1, 1, 0><<<dim3(MM / 64, BB / 64), 256, 0, stream>>>(
            x, c, fc_w, fc_b, hidx, nullptr, MM, KXC);
        softmax3_k<<<BB, 256, 0, stream>>>(hidx);
        hentry3_k<<<BB, 512, 0, stream>>>(hidx, hmem, concatb);
        mgemm3_k<0, 0, 1><<<dim3(NG / 64, BB / 64), 256, 0, stream>>>(
            concatb, nullptr, W_full1, bias1, gated, concatb, NG, KCAT);
        mgemm3_k<0, 0, 0><<<dim3(NFULL / 64, BB / 64), 256, 0, stream>>>(
            gated, nullptr, W_full, bias, pre, nullptr, NFULL, KCAT);
        lstm3_k<<<BB * 1536 / 256, 256, 0, stream>>>(pre, c, concatb, out);
        mgemm3_k<1, 1, 0><<<dim3(RR / 64, BB / 64), 256, 0, stream>>>(
            x, new_c, trans_w, trans_b, wval, nullptr, RR, KXC);
        hmemupd_k<<<4096, 256, 0, stream>>>(hmem, wval, hidx, out + OFF_HM);
    }
}

// Round 17
// 339.920 us; speedup vs baseline: 1.5773x; 1.5773x over previous
//
#include <hip/hip_runtime.h>
#include <hip/hip_bf16.h>
#include <cstddef>

// Problem constants
#define BB 256
#define XX 512
#define HH 1024
#define RR 512
#define MM 512
// derived
#define KCAT 2048          // X + H + R
#define KXC 1536           // X + H
#define NFULL 4608         // R + 4H
#define NG 1536            // R + H

// d_out offsets (floats)
#define OFF_NH (BB*1536)                 // 393216
#define OFF_NC (OFF_NH + BB*HH)          // 655360
#define OFF_HM (OFF_NC + BB*HH)          // 917504

typedef __attribute__((ext_vector_type(8))) short bf16x8;
typedef __attribute__((ext_vector_type(4))) short s16x4;
typedef __attribute__((ext_vector_type(4))) float f32x4;

__device__ __forceinline__ float sigm(float x) { return 1.0f / (1.0f + expf(-x)); }

// fp32 -> bf16 bits, round-to-nearest-even (finite values)
__device__ __forceinline__ unsigned short f2bf(float f) {
    unsigned u = __float_as_uint(f);
    u = u + 0x7fffu + ((u >> 16) & 1u);
    return (unsigned short)(u >> 16);
}
__device__ __forceinline__ float bf2f(unsigned short h) {
    return __uint_as_float((unsigned)h << 16);
}

// ===========================================================================
// ===============            MAIN (pre-split) PATH            ===============
// ===========================================================================

// Straight convert: src [n] f32 -> hi/lo bf16 (same layout). 8 elems/thread.
__global__ __launch_bounds__(256) void convw_k(const float* __restrict__ src,
                                               short* __restrict__ hi,
                                               short* __restrict__ lo,
                                               int n8) {
    int i = blockIdx.x * 256 + threadIdx.x;
    if (i >= n8) return;
    size_t e0 = (size_t)i * 8;
    short hs[8], ls[8];
    #pragma unroll
    for (int q = 0; q < 2; ++q) {
        float4 v = reinterpret_cast<const float4*>(src + e0)[q];
        float f[4] = {v.x, v.y, v.z, v.w};
        #pragma unroll
        for (int e = 0; e < 4; ++e) {
            unsigned short hb = f2bf(f[e]);
            hs[q * 4 + e] = (short)hb;
            ls[q * 4 + e] = (short)f2bf(f[e] - bf2f(hb));
        }
    }
    *reinterpret_cast<bf16x8*>(hi + e0) = *reinterpret_cast<bf16x8*>(&hs[0]);
    *reinterpret_cast<bf16x8*>(lo + e0) = *reinterpret_cast<bf16x8*>(&ls[0]);
}

// Transpose-convert: W [Kdim][Ndim] f32 -> Thi/Tlo [Ndim][Kdim] bf16.
// 64x64 tiles; LDS staged.
__global__ __launch_bounds__(256) void convt_k(const float* __restrict__ W,
                                               int Kdim, int Ndim,
                                               short* __restrict__ Thi,
                                               short* __restrict__ Tlo) {
    __shared__ __align__(16) short lh[64][72];
    __shared__ __align__(16) short ll[64][72];
    const int tid = threadIdx.x;
    const int k0 = blockIdx.x * 64, n0 = blockIdx.y * 64;
    {
        int kr = (tid >> 4) * 4;          // 0..60
        int nc = (tid & 15) * 4;          // 0..60
        #pragma unroll
        for (int i = 0; i < 4; ++i) {
            float4 v = *reinterpret_cast<const float4*>(W + (size_t)(k0 + kr + i) * Ndim + n0 + nc);
            float f[4] = {v.x, v.y, v.z, v.w};
            #pragma unroll
            for (int e = 0; e < 4; ++e) {
                unsigned short hb = f2bf(f[e]);
                lh[nc + e][kr + i] = (short)hb;
                ll[nc + e][kr + i] = (short)f2bf(f[e] - bf2f(hb));
            }
        }
    }
    __syncthreads();
    {
        int nl = tid >> 2;                // 0..63
        int kq = (tid & 3) * 16;          // 0..48
        size_t base = (size_t)(n0 + nl) * Kdim + k0 + kq;
        *reinterpret_cast<bf16x8*>(Thi + base)     = *reinterpret_cast<const bf16x8*>(&lh[nl][kq]);
        *reinterpret_cast<bf16x8*>(Thi + base + 8) = *reinterpret_cast<const bf16x8*>(&lh[nl][kq + 8]);
        *reinterpret_cast<bf16x8*>(Tlo + base)     = *reinterpret_cast<const bf16x8*>(&ll[nl][kq]);
        *reinterpret_cast<bf16x8*>(Tlo + base + 8) = *reinterpret_cast<const bf16x8*>(&ll[nl][kq + 8]);
    }
}

// prep: cat[:,0:1536] = [x|c] (hi/lo); x also into gat[:,0:512], xnc[:,0:512]
__global__ __launch_bounds__(256) void prep_k(const float* __restrict__ x,
                                              const float* __restrict__ c,
                                              short* __restrict__ cat_hi, short* __restrict__ cat_lo,
                                              short* __restrict__ gat_hi, short* __restrict__ gat_lo,
                                              short* __restrict__ xnc_hi, short* __restrict__ xnc_lo) {
    int i = blockIdx.x * 256 + threadIdx.x;       // B*1536/4 threads
    int e0 = i * 4;
    int b = e0 / KXC, q = e0 - b * KXC;
    float4 v = (q < XX) ? *reinterpret_cast<const float4*>(x + (size_t)b * XX + q)
                        : *reinterpret_cast<const float4*>(c + (size_t)b * HH + (q - XX));
    float f[4] = {v.x, v.y, v.z, v.w};
    s16x4 hv, lv;
    #pragma unroll
    for (int e = 0; e < 4; ++e) {
        unsigned short hb = f2bf(f[e]);
        hv[e] = (short)hb;
        lv[e] = (short)f2bf(f[e] - bf2f(hb));
    }
    *reinterpret_cast<s16x4*>(cat_hi + (size_t)b * KCAT + q) = hv;
    *reinterpret_cast<s16x4*>(cat_lo + (size_t)b * KCAT + q) = lv;
    if (q < XX) {
        *reinterpret_cast<s16x4*>(gat_hi + (size_t)b * KCAT + q) = hv;
        *reinterpret_cast<s16x4*>(gat_lo + (size_t)b * KCAT + q) = lv;
        *reinterpret_cast<s16x4*>(xnc_hi + (size_t)b * KXC + q) = hv;
        *reinterpret_cast<s16x4*>(xnc_lo + (size_t)b * KXC + q) = lv;
    }
}

// MFMA GEMM on pre-split bf16 hi/lo operands.
// A: [row][lda] hi/lo, B: [n][K] hi/lo. 64x64 tile, BK=64, 4 waves (2x2),
// wave 32x32 = 2x2 frags of v_mfma_f32_16x16x32_bf16, 3 passes hh+hl+lh.
// Single-buffered (measured optimal: reg-prefetch variant costs +195us).
// EPI 0: C[row*ldc+col] = acc + bias[col]
// EPI 1: gate: e=cat[row][512+col]; gat[row][512+col] = split(e*sigm(acc+bias))
template<int EPI>
__global__ __launch_bounds__(256) void mgemm_ps(const short* __restrict__ Ahi,
                                                const short* __restrict__ Alo, int lda,
                                                const short* __restrict__ Bhi,
                                                const short* __restrict__ Blo,
                                                const float* __restrict__ bias,
                                                float* __restrict__ C, int ldc,
                                                const short* __restrict__ cat_hi,
                                                const short* __restrict__ cat_lo,
                                                short* __restrict__ gat_hi,
                                                short* __restrict__ gat_lo,
                                                int K) {
    __shared__ __align__(16) short Ah[64][72];
    __shared__ __align__(16) short Al[64][72];
    __shared__ __align__(16) short Bh[64][72];
    __shared__ __align__(16) short Bl[64][72];

    const int tid = threadIdx.x;
    const int row0 = blockIdx.y * 64, col0 = blockIdx.x * 64;
    const int lane = tid & 63, w = tid >> 6;
    const int rm = (w >> 1) * 32, cn = (w & 1) * 32;
    const int fr = lane & 15;
    const int kg = lane >> 4;

    const int ar = tid >> 2;              // 0..63
    const int akq = (tid & 3) * 16;       // 0..48

    f32x4 acc[2][2] = {};

    for (int k0 = 0; k0 < K; k0 += 64) {
        {   // stage A
            size_t base = (size_t)(row0 + ar) * lda + k0 + akq;
            bf16x8 h0 = *reinterpret_cast<const bf16x8*>(Ahi + base);
            bf16x8 h1 = *reinterpret_cast<const bf16x8*>(Ahi + base + 8);
            bf16x8 l0 = *reinterpret_cast<const bf16x8*>(Alo + base);
            bf16x8 l1 = *reinterpret_cast<const bf16x8*>(Alo + base + 8);
            *reinterpret_cast<bf16x8*>(&Ah[ar][akq])     = h0;
            *reinterpret_cast<bf16x8*>(&Ah[ar][akq + 8]) = h1;
            *reinterpret_cast<bf16x8*>(&Al[ar][akq])     = l0;
            *reinterpret_cast<bf16x8*>(&Al[ar][akq + 8]) = l1;
        }
        {   // stage B
            size_t base = (size_t)(col0 + ar) * K + k0 + akq;
            bf16x8 h0 = *reinterpret_cast<const bf16x8*>(Bhi + base);
            bf16x8 h1 = *reinterpret_cast<const bf16x8*>(Bhi + base + 8);
            bf16x8 l0 = *reinterpret_cast<const bf16x8*>(Blo + base);
            bf16x8 l1 = *reinterpret_cast<const bf16x8*>(Blo + base + 8);
            *reinterpret_cast<bf16x8*>(&Bh[ar][akq])     = h0;
            *reinterpret_cast<bf16x8*>(&Bh[ar][akq + 8]) = h1;
            *reinterpret_cast<bf16x8*>(&Bl[ar][akq])     = l0;
            *reinterpret_cast<bf16x8*>(&Bl[ar][akq + 8]) = l1;
        }
        __syncthreads();

        #pragma unroll
        for (int ks = 0; ks < 64; ks += 32) {
            bf16x8 ah[2], al[2], bh[2], bl[2];
            #pragma unroll
            for (int mf = 0; mf < 2; ++mf) {
                ah[mf] = *reinterpret_cast<const bf16x8*>(&Ah[rm + mf * 16 + fr][ks + kg * 8]);
                al[mf] = *reinterpret_cast<const bf16x8*>(&Al[rm + mf * 16 + fr][ks + kg * 8]);
            }
            #pragma unroll
            for (int nf = 0; nf < 2; ++nf) {
                bh[nf] = *reinterpret_cast<const bf16x8*>(&Bh[cn + nf * 16 + fr][ks + kg * 8]);
                bl[nf] = *reinterpret_cast<const bf16x8*>(&Bl[cn + nf * 16 + fr][ks + kg * 8]);
            }
            #pragma unroll
            for (int mf = 0; mf < 2; ++mf)
                #pragma unroll
                for (int nf = 0; nf < 2; ++nf) {
                    acc[mf][nf] = __builtin_amdgcn_mfma_f32_16x16x32_bf16(ah[mf], bh[nf], acc[mf][nf], 0, 0, 0);
                    acc[mf][nf] = __builtin_amdgcn_mfma_f32_16x16x32_bf16(ah[mf], bl[nf], acc[mf][nf], 0, 0, 0);
                    acc[mf][nf] = __builtin_amdgcn_mfma_f32_16x16x32_bf16(al[mf], bh[nf], acc[mf][nf], 0, 0, 0);
                }
        }
        __syncthreads();
    }

    #pragma unroll
    for (int mf = 0; mf < 2; ++mf)
        #pragma unroll
        for (int nf = 0; nf < 2; ++nf)
            #pragma unroll
            for (int i = 0; i < 4; ++i) {
                int row = row0 + rm + mf * 16 + kg * 4 + i;
                int col = col0 + cn + nf * 16 + fr;
                float v = acc[mf][nf][i] + bias[col];
                if (EPI == 0) {
                    C[(size_t)row * ldc + col] = v;
                } else {
                    size_t base = (size_t)row * KCAT + XX + col;
                    float e = bf2f((unsigned short)cat_hi[base]) + bf2f((unsigned short)cat_lo[base]);
                    float gv = e * sigm(v);
                    unsigned short hb = f2bf(gv);
                    gat_hi[base] = (short)hb;
                    gat_lo[base] = (short)f2bf(gv - bf2f(hb));
                }
            }
}

// fused softmax + h_entry: block b, 512 threads.
__global__ __launch_bounds__(512) void smhe_k(const float* __restrict__ rh,
                                              const float* __restrict__ hmem,
                                              float* __restrict__ hidx,
                                              short* __restrict__ cat_hi,
                                              short* __restrict__ cat_lo) {
    __shared__ float red[8];
    __shared__ float red2[8];
    __shared__ float wiL[MM];
    int b = blockIdx.x, t = threadIdx.x;
    float v = rh[(size_t)b * MM + t];
    float m = v;
    #pragma unroll
    for (int off = 1; off < 64; off <<= 1) m = fmaxf(m, __shfl_xor(m, off));
    int wid = t >> 6, lane = t & 63;
    if (lane == 0) red[wid] = m;
    __syncthreads();
    float mm = red[0];
    #pragma unroll
    for (int i = 1; i < 8; ++i) mm = fmaxf(mm, red[i]);
    float e = expf(v - mm);
    float s = e;
    #pragma unroll
    for (int off = 1; off < 64; off <<= 1) s += __shfl_xor(s, off);
    if (lane == 0) red2[wid] = s;
    __syncthreads();
    float tot = red2[0];
    #pragma unroll
    for (int i = 1; i < 8; ++i) tot += red2[i];
    float wi = e / tot;
    hidx[(size_t)b * MM + t] = wi;
    wiL[t] = wi;
    __syncthreads();
    // h_entry[b][t] = sum_m wi[m] * hmem[b][m][t]
    const float* hm = hmem + (size_t)b * MM * RR + t;
    float acc = 0.f;
    #pragma unroll 8
    for (int m2 = 0; m2 < MM; ++m2) acc += wiL[m2] * hm[(size_t)m2 * RR];
    size_t base = (size_t)b * KCAT + KXC + t;
    unsigned short hb = f2bf(acc);
    cat_hi[base] = (short)hb;
    cat_lo[base] = (short)f2bf(acc - bf2f(hb));
}

// LSTM elementwise; writes new_r/new_h/new_c and xnc[:,512:1536] = split(new_c)
__global__ __launch_bounds__(256) void lstm_k(const float* __restrict__ pre,
                                              const float* __restrict__ c,
                                              const short* __restrict__ cat_hi,
                                              const short* __restrict__ cat_lo,
                                              float* __restrict__ out,
                                              short* __restrict__ xnc_hi,
                                              short* __restrict__ xnc_lo) {
    int idx = blockIdx.x * 256 + threadIdx.x;   // B*1536
    int b = idx / 1536, q = idx - b * 1536;
    const float* p = pre + (size_t)b * NFULL;
    if (q < HH) {
        float iv = p[q], jv = p[HH + q], fv = p[2 * HH + q], ov = p[3 * HH + q];
        float cc = c[(size_t)b * HH + q];
        float nc = tanhf(cc * sigm(fv + 1.0f) + sigm(iv) * tanhf(jv));
        float nh = nc * sigm(ov);
        out[(size_t)b * 1536 + q] = nh;
        out[OFF_NH + (size_t)b * HH + q] = nh;
        out[OFF_NC + (size_t)b * HH + q] = nc;
        unsigned short hb = f2bf(nc);
        xnc_hi[(size_t)b * KXC + XX + q] = (short)hb;
        xnc_lo[(size_t)b * KXC + XX + q] = (short)f2bf(nc - bf2f(hb));
    } else {
        int r = q - HH;
        float om = p[4 * HH + r];
        size_t base = (size_t)b * KCAT + KXC + r;
        float he = bf2f((unsigned short)cat_hi[base]) + bf2f((unsigned short)cat_lo[base]);
        out[(size_t)b * 1536 + HH + r] = he * sigm(om);
    }
}

// new_hmem = w_val[:,None,:]*w_idx[:,:,None] + hmem*(1-w_idx)
// (grid-stride form: lockstep dense streaming — measured optimal)
__global__ __launch_bounds__(256) void hmemupd_k(const float* __restrict__ hmem,
                                                 const float* __restrict__ wval,
                                                 const float* __restrict__ widx,
                                                 float* __restrict__ outhm) {
    size_t n4 = (size_t)BB * MM * RR / 4;
    size_t stride = (size_t)gridDim.x * blockDim.x;
    for (size_t i = (size_t)blockIdx.x * blockDim.x + threadIdx.x; i < n4; i += stride) {
        size_t e = i * 4;
        int r = (int)(e & (RR - 1));
        int m = (int)((e >> 9) & (MM - 1));
        int b = (int)(e >> 18);
        float wi = widx[(size_t)b * MM + m];
        float om = 1.0f - wi;
        float4 hv = *reinterpret_cast<const float4*>(hmem + e);
        float4 wv = *reinterpret_cast<const float4*>(wval + (size_t)b * RR + r);
        float4 o;
        o.x = wv.x * wi + hv.x * om;
        o.y = wv.y * wi + hv.y * om;
        o.z = wv.z * wi + hv.z * om;
        o.w = wv.w * wi + hv.w * om;
        *reinterpret_cast<float4*>(outhm + e) = o;
    }
}

// ===========================================================================
// ===============     FALLBACK (round-3, split-in-loop)       ===============
// ===========================================================================

__global__ __launch_bounds__(256) void prep3_k(const float* __restrict__ x,
                                               const float* __restrict__ c,
                                               float* __restrict__ concatb,
                                               float* __restrict__ gated) {
    int idx = blockIdx.x * 256 + threadIdx.x;
    int b = idx / KXC, q = idx - b * KXC;
    float v;
    if (q < XX) { v = x[b * XX + q]; gated[(size_t)b * KCAT + q] = v; }
    else v = c[b * HH + (q - XX)];
    concatb[(size_t)b * KCAT + q] = v;
}

template<int AMODE, int BLAYOUT, int EPI>
__global__ __launch_bounds__(256) void mgemm3_k(const float* __restrict__ A0,
                                                const float* __restrict__ A1,
                                                const float* __restrict__ W,
                                                const float* __restrict__ bias,
                                                float* __restrict__ C,
                                                const float* __restrict__ E,
                                                int N, int K) {
    __shared__ __align__(16) short Ah[64][72];
    __shared__ __align__(16) short Al[64][72];
    __shared__ __align__(16) short Bh[64][72];
    __shared__ __align__(16) short Bl[64][72];
    const int tid = threadIdx.x;
    const int row0 = blockIdx.y * 64, col0 = blockIdx.x * 64;
    const int lane = tid & 63, w = tid >> 6;
    const int rm = (w >> 1) * 32, cn = (w & 1) * 32;
    const int fr = lane & 15, kg = lane >> 4;
    const int ar = tid >> 2, akq = (tid & 3) * 16;
    const int bkk = (tid >> 4) * 4, bnn = (tid & 15) * 4;
    f32x4 acc[2][2] = {};
    for (int k0 = 0; k0 < K; k0 += 64) {
        {
            const float* src;
            if (AMODE == 0) src = A0 + (size_t)(row0 + ar) * K + k0 + akq;
            else {
                int gk = k0 + akq;
                src = (gk < XX) ? (A0 + (size_t)(row0 + ar) * XX + gk)
                                : (A1 + (size_t)(row0 + ar) * HH + (gk - XX));
            }
            short hs[16], ls[16];
            #pragma unroll
            for (int q = 0; q < 4; ++q) {
                float4 v = reinterpret_cast<const float4*>(src)[q];
                float f[4] = {v.x, v.y, v.z, v.w};
                #pragma unroll
                for (int e = 0; e < 4; ++e) {
                    unsigned short hb = f2bf(f[e]);
                    hs[q * 4 + e] = (short)hb;
                    ls[q * 4 + e] = (short)f2bf(f[e] - bf2f(hb));
                }
            }
            *reinterpret_cast<bf16x8*>(&Ah[ar][akq])     = *reinterpret_cast<bf16x8*>(&hs[0]);
            *reinterpret_cast<bf16x8*>(&Ah[ar][akq + 8]) = *reinterpret_cast<bf16x8*>(&hs[8]);
            *reinterpret_cast<bf16x8*>(&Al[ar][akq])     = *reinterpret_cast<bf16x8*>(&ls[0]);
            *reinterpret_cast<bf16x8*>(&Al[ar][akq + 8]) = *reinterpret_cast<bf16x8*>(&ls[8]);
        }
        if (BLAYOUT == 1) {
            const float* src = W + (size_t)(col0 + ar) * K + k0 + akq;
            short hs[16], ls[16];
            #pragma unroll
            for (int q = 0; q < 4; ++q) {
                float4 v = reinterpret_cast<const float4*>(src)[q];
                float f[4] = {v.x, v.y, v.z, v.w};
                #pragma unroll
                for (int e = 0; e < 4; ++e) {
                    unsigned short hb = f2bf(f[e]);
                    hs[q * 4 + e] = (short)hb;
                    ls[q * 4 + e] = (short)f2bf(f[e] - bf2f(hb));
                }
            }
            *reinterpret_cast<bf16x8*>(&Bh[ar][akq])     = *reinterpret_cast<bf16x8*>(&hs[0]);
            *reinterpret_cast<bf16x8*>(&Bh[ar][akq + 8]) = *reinterpret_cast<bf16x8*>(&hs[8]);
            *reinterpret_cast<bf16x8*>(&Bl[ar][akq])     = *reinterpret_cast<bf16x8*>(&ls[0]);
            *reinterpret_cast<bf16x8*>(&Bl[ar][akq + 8]) = *reinterpret_cast<bf16x8*>(&ls[8]);
        } else {
            float4 r0 = *reinterpret_cast<const float4*>(W + (size_t)(k0 + bkk + 0) * N + col0 + bnn);
            float4 r1 = *reinterpret_cast<const float4*>(W + (size_t)(k0 + bkk + 1) * N + col0 + bnn);
            float4 r2 = *reinterpret_cast<const float4*>(W + (size_t)(k0 + bkk + 2) * N + col0 + bnn);
            float4 r3 = *reinterpret_cast<const float4*>(W + (size_t)(k0 + bkk + 3) * N + col0 + bnn);
            float col[4][4] = {{r0.x, r1.x, r2.x, r3.x}, {r0.y, r1.y, r2.y, r3.y},
                               {r0.z, r1.z, r2.z, r3.z}, {r0.w, r1.w, r2.w, r3.w}};
            #pragma unroll
            for (int j = 0; j < 4; ++j) {
                s16x4 hv, lv;
                #pragma unroll
                for (int e = 0; e < 4; ++e) {
                    unsigned short hb = f2bf(col[j][e]);
                    hv[e] = (short)hb;
                    lv[e] = (short)f2bf(col[j][e] - bf2f(hb));
                }
                *reinterpret_cast<s16x4*>(&Bh[bnn + j][bkk]) = hv;
                *reinterpret_cast<s16x4*>(&Bl[bnn + j][bkk]) = lv;
            }
        }
        __syncthreads();
        #pragma unroll
        for (int ks = 0; ks < 64; ks += 32) {
            bf16x8 ah[2], al[2], bh[2], bl[2];
            #pragma unroll
            for (int mf = 0; mf < 2; ++mf) {
                ah[mf] = *reinterpret_cast<const bf16x8*>(&Ah[rm + mf * 16 + fr][ks + kg * 8]);
                al[mf] = *reinterpret_cast<const bf16x8*>(&Al[rm + mf * 16 + fr][ks + kg * 8]);
            }
            #pragma unroll
            for (int nf = 0; nf < 2; ++nf) {
                bh[nf] = *reinterpret_cast<const bf16x8*>(&Bh[cn + nf * 16 + fr][ks + kg * 8]);
                bl[nf] = *reinterpret_cast<const bf16x8*>(&Bl[cn + nf * 16 + fr][ks + kg * 8]);
            }
            #pragma unroll
            for (int mf = 0; mf < 2; ++mf)
                #pragma unroll
                for (int nf = 0; nf < 2; ++nf) {
                    acc[mf][nf] = __builtin_amdgcn_mfma_f32_16x16x32_bf16(ah[mf], bh[nf], acc[mf][nf], 0, 0, 0);
                    acc[mf][nf] = __builtin_amdgcn_mfma_f32_16x16x32_bf16(ah[mf], bl[nf], acc[mf][nf], 0, 0, 0);
                    acc[mf][nf] = __builtin_amdgcn_mfma_f32_16x16x32_bf16(al[mf], bh[nf], acc[mf][nf], 0, 0, 0);
                }
        }
        __syncthreads();
    }
    #pragma unroll
    for (int mf = 0; mf < 2; ++mf)
        #pragma unroll
        for (int nf = 0; nf < 2; ++nf)
            #pragma unroll
            for (int i = 0; i < 4; ++i) {
                int row = row0 + rm + mf * 16 + kg * 4 + i;
                int col = col0 + cn + nf * 16 + fr;
                float v = acc[mf][nf][i] + bias[col];
                if (EPI == 0) C[(size_t)row * N + col] = v;
                else {
                    size_t base = (size_t)row * KCAT + XX + col;
                    C[base] = E[base] * sigm(v);
                }
            }
}

__global__ __launch_bounds__(256) void softmax3_k(float* __restrict__ rh) {
    int b = blockIdx.x;
    float* row = rh + (size_t)b * MM;
    int t = threadIdx.x;
    float v0 = row[t], v1 = row[t + 256];
    float m = fmaxf(v0, v1);
    #pragma unroll
    for (int off = 1; off < 64; off <<= 1) m = fmaxf(m, __shfl_xor(m, off));
    __shared__ float red[8];
    int wid = t >> 6, lane = t & 63;
    if (lane == 0) red[wid] = m;
    __syncthreads();
    float mm = fmaxf(fmaxf(red[0], red[1]), fmaxf(red[2], red[3]));
    float e0 = expf(v0 - mm), e1 = expf(v1 - mm);
    float s = e0 + e1;
    #pragma unroll
    for (int off = 1; off < 64; off <<= 1) s += __shfl_xor(s, off);
    if (lane == 0) red[4 + wid] = s;
    __syncthreads();
    float inv = 1.0f / (red[4] + red[5] + red[6] + red[7]);
    row[t] = e0 * inv;
    row[t + 256] = e1 * inv;
}

__global__ __launch_bounds__(512) void hentry3_k(const float* __restrict__ hidx,
                                                 const float* __restrict__ hmem,
                                                 float* __restrict__ concatb) {
    int b = blockIdx.x;
    int r = threadIdx.x;
    __shared__ float wi[MM];
    wi[r] = hidx[(size_t)b * MM + r];
    __syncthreads();
    const float* hm = hmem + (size_t)b * MM * RR + r;
    float acc = 0.f;
    #pragma unroll 8
    for (int m = 0; m < MM; ++m) acc += wi[m] * hm[(size_t)m * RR];
    concatb[(size_t)b * KCAT + KXC + r] = acc;
}

__global__ __launch_bounds__(256) void lstm3_k(const float* __restrict__ pre,
                                               const float* __restrict__ c,
                                               const float* __restrict__ concatb,
                                               float* __restrict__ out) {
    int idx = blockIdx.x * 256 + threadIdx.x;
    int b = idx / 1536, q = idx - b * 1536;
    const float* p = pre + (size_t)b * NFULL;
    if (q < HH) {
        float iv = p[q], jv = p[HH + q], fv = p[2 * HH + q], ov = p[3 * HH + q];
        float cc = c[(size_t)b * HH + q];
        float nc = tanhf(cc * sigm(fv + 1.0f) + sigm(iv) * tanhf(jv));
        float nh = nc * sigm(ov);
        out[(size_t)b * 1536 + q] = nh;
        out[OFF_NH + (size_t)b * HH + q] = nh;
        out[OFF_NC + (size_t)b * HH + q] = nc;
    } else {
        int r = q - HH;
        float om = p[4 * HH + r];
        float he = concatb[(size_t)b * KCAT + KXC + r];
        out[(size_t)b * 1536 + HH + r] = he * sigm(om);
    }
}

// ===========================================================================
extern "C" void kernel_launch(void* const* d_in, const int* in_sizes, int n_in,
                              void* d_out, int out_size, void* d_ws, size_t ws_size,
                              hipStream_t stream) {
    const float* x      = (const float*)d_in[0];
    const float* c      = (const float*)d_in[2];
    const float* hmem   = (const float*)d_in[3];
    const float* W_full = (const float*)d_in[4];
    const float* bias   = (const float*)d_in[5];
    const float* W_full1= (const float*)d_in[6];
    const float* bias1  = (const float*)d_in[7];
    const float* trans_w= (const float*)d_in[8];
    const float* trans_b= (const float*)d_in[9];
    const float* fc_w   = (const float*)d_in[10];
    const float* fc_b   = (const float*)d_in[11];

    float* out = (float*)d_out;

    // ---- new-path workspace layout (bytes)
    constexpr size_t SZ_WT  = (size_t)NFULL * KCAT * 2;
    constexpr size_t SZ_WT1 = (size_t)NG * KCAT * 2;
    constexpr size_t SZ_FCW = (size_t)MM * KXC * 2;
    constexpr size_t SZ_TRW = (size_t)RR * KXC * 2;
    constexpr size_t SZ_CAT = (size_t)BB * KCAT * 2;
    constexpr size_t SZ_XNC = (size_t)BB * KXC * 2;
    constexpr size_t SZ_RH  = (size_t)BB * MM * 4;
    constexpr size_t SZ_PRE = (size_t)BB * NFULL * 4;
    constexpr size_t NEED = 2*SZ_WT + 2*SZ_WT1 + 2*SZ_FCW + 2*SZ_TRW
                          + 4*SZ_CAT + 2*SZ_XNC + 2*SZ_RH + SZ_PRE + SZ_RH;

    if (ws_size >= NEED) {
        char* p = (char*)d_ws;
        short* wt_hi  = (short*)p; p += SZ_WT;
        short* wt_lo  = (short*)p; p += SZ_WT;
        short* wt1_hi = (short*)p; p += SZ_WT1;
        short* wt1_lo = (short*)p; p += SZ_WT1;
        short* fcw_hi = (short*)p; p += SZ_FCW;
        short* fcw_lo = (short*)p; p += SZ_FCW;
        short* trw_hi = (short*)p; p += SZ_TRW;
        short* trw_lo = (short*)p; p += SZ_TRW;
        short* cat_hi = (short*)p; p += SZ_CAT;
        short* cat_lo = (short*)p; p += SZ_CAT;
        short* gat_hi = (short*)p; p += SZ_CAT;
        short* gat_lo = (short*)p; p += SZ_CAT;
        short* xnc_hi = (short*)p; p += SZ_XNC;
        short* xnc_lo = (short*)p; p += SZ_XNC;
        float* rh     = (float*)p; p += SZ_RH;
        float* hidx   = (float*)p; p += SZ_RH;
        float* pre    = (float*)p; p += SZ_PRE;
        float* wval   = (float*)p;

        // weight conversion (every call; deterministic)
        convt_k<<<dim3(KCAT / 64, NFULL / 64), 256, 0, stream>>>(W_full, KCAT, NFULL, wt_hi, wt_lo);
        convt_k<<<dim3(KCAT / 64, NG / 64), 256, 0, stream>>>(W_full1, KCAT, NG, wt1_hi, wt1_lo);
        convw_k<<<(MM * KXC / 8 + 255) / 256, 256, 0, stream>>>(fc_w, fcw_hi, fcw_lo, MM * KXC / 8);
        convw_k<<<(RR * KXC / 8 + 255) / 256, 256, 0, stream>>>(trans_w, trw_hi, trw_lo, RR * KXC / 8);

        prep_k<<<BB * KXC / 4 / 256, 256, 0, stream>>>(x, c, cat_hi, cat_lo, gat_hi, gat_lo, xnc_hi, xnc_lo);

        // read_head = [x|c] @ fc_w^T + fc_b
        mgemm_ps<0><<<dim3(MM / 64, BB / 64), 256, 0, stream>>>(
            cat_hi, cat_lo, KCAT, fcw_hi, fcw_lo, fc_b, rh, MM,
            nullptr, nullptr, nullptr, nullptr, KXC);

        smhe_k<<<BB, 512, 0, stream>>>(rh, hmem, hidx, cat_hi, cat_lo);

        // gate GEMM with split-epilogue into gat
        mgemm_ps<1><<<dim3(NG / 64, BB / 64), 256, 0, stream>>>(
            cat_hi, cat_lo, KCAT, wt1_hi, wt1_lo, bias1, nullptr, 0,
            cat_hi, cat_lo, gat_hi, gat_lo, KCAT);

        // pre = gated @ W_full + bias
        mgemm_ps<0><<<dim3(NFULL / 64, BB / 64), 256, 0, stream>>>(
            gat_hi, gat_lo, KCAT, wt_hi, wt_lo, bias, pre, NFULL,
            nullptr, nullptr, nullptr, nullptr, KCAT);

        lstm_k<<<BB * 1536 / 256, 256, 0, stream>>>(pre, c, cat_hi, cat_lo, out, xnc_hi, xnc_lo);

        // w_val = [x|new_c] @ trans_w^T + trans_b
        mgemm_ps<0><<<dim3(RR / 64, BB / 64), 256, 0, stream>>>(
            xnc_hi, xnc_lo, KXC, trw_hi, trw_lo, trans_b, wval, RR,
            nullptr, nullptr, nullptr, nullptr, KXC);

        // hmem blend
        hmemupd_k<<<4096, 256, 0, stream>>>(hmem, wval, hidx, out + OFF_HM);
    } else {
        // -------- fallback: round-3 path (~10 MB ws) --------
        float* ws   = (float*)d_ws;
        float* hidx    = ws;
        float* concatb = hidx + BB * MM;
        float* gated   = concatb + BB * KCAT;
        float* pre     = gated + BB * KCAT;
        float* wval    = pre + BB * NFULL;
        float* new_c   = out + OFF_NC;

        prep3_k<<<BB * KXC / 256, 256, 0, stream>>>(x, c, concatb, gated);
        mgemm3_k<1, 1, 0><<<dim3(MM / 64, BB / 64), 256, 0, stream>>>(
            x, c, fc_w, fc_b, hidx, nullptr, MM, KXC);
        softmax3_k<<<BB, 256, 0, stream>>>(hidx);
        hentry3_k<<<BB, 512, 0, stream>>>(hidx, hmem, concatb);
        mgemm3_k<0, 0, 1><<<dim3(NG / 64, BB / 64), 256, 0, stream>>>(
            concatb, nullptr, W_full1, bias1, gated, concatb, NG, KCAT);
        mgemm3_k<0, 0, 0><<<dim3(NFULL / 64, BB / 64), 256, 0, stream>>>(
            gated, nullptr, W_full, bias, pre, nullptr, NFULL, KCAT);
        lstm3_k<<<BB * 1536 / 256, 256, 0, stream>>>(pre, c, concatb, out);
        mgemm3_k<1, 1, 0><<<dim3(RR / 64, BB / 64), 256, 0, stream>>>(
            x, new_c, trans_w, trans_b, wval, nullptr, RR, KXC);
        hmemupd_k<<<4096, 256, 0, stream>>>(hmem, wval, hidx, out + OFF_HM);
    }
}